// Round 13
// baseline (1840.933 us; speedup 1.0000x reference)
//
#include <hip/hip_runtime.h>
#include <hip/hip_bf16.h>
#include <math.h>

// Problem constants
constexpr int cB = 8, cSE = 2048, cSD = 1024, cIN = 1280, cD = 512,
              cDEPTH = 4, cH = 8, cDH = 64, cM = 266, cFF = 2048, cNB = 128;
constexpr int cMP = 288;  // cM padded to multiple of 16 (features pad -> 0)

#define DEV __device__ __forceinline__

typedef __bf16 bf16;
typedef __attribute__((ext_vector_type(8))) __bf16 bf16x8;
typedef __attribute__((ext_vector_type(4))) __bf16 bf16x4;
typedef __attribute__((ext_vector_type(2))) __bf16 bf16x2;
typedef __attribute__((ext_vector_type(4))) float f32x4;

DEV float gelu_f(float x) { return 0.5f * x * (1.0f + erff(x * 0.70710678118654752440f)); }

DEV float wave_sum(float v) {
#pragma unroll
  for (int o = 32; o; o >>= 1) v += __shfl_xor(v, o);
  return v;
}
DEV float wave_max(float v) {
#pragma unroll
  for (int o = 32; o; o >>= 1) v = fmaxf(v, __shfl_xor(v, o));
  return v;
}

#define GL2LDS(gp, lp) __builtin_amdgcn_global_load_lds(                    \
    (const __attribute__((address_space(1))) void*)(gp),                    \
    (__attribute__((address_space(3))) void*)(lp), 16, 0, 0)

// ---------------------------------------------------------------------------
// bf16 MFMA GEMM, BK=64 dual-panel staging, XCD-aware bijective swizzle.
// C[M,N] = epi(A[M,K] @ Bt[N,K]^T). M%128==0, N%128==0, K%64==0.
// OUT: 0=f32 C (+RES f32), 1=bf16 C, 3=bf16 C with bf16 residual RMW.
// ACT: 1 = exact GELU, 2 = scale by 0.125*log2(e) (flash Q prescale).
// ---------------------------------------------------------------------------
template <int OUT, int ACT, bool BIAS, bool RES>
__global__ __launch_bounds__(256) void gemm_mfma(
    const bf16* __restrict__ A, const bf16* __restrict__ Bt,
    void* __restrict__ Cv, bf16* __restrict__ Cv2,
    const float* __restrict__ bias, int M, int N, int K) {
  __shared__ bf16 As[2 * 128 * 32];  // two K-half panels, each [128][32]
  __shared__ bf16 Bs[2 * 128 * 32];
  const int t = threadIdx.x, l = t & 63, w = t >> 6;
  const int g = l >> 4, c = l & 15;
  const int nwg = gridDim.x * gridDim.y;
  int id = blockIdx.y * gridDim.x + blockIdx.x;
  if ((nwg & 7) == 0) id = (id & 7) * (nwg >> 3) + (id >> 3);
  const int m0 = (id / gridDim.x) * 128, n0 = (id % gridDim.x) * 128;
  const int wr = (w >> 1) * 64, wc = (w & 1) * 64;
  const int srow = w * 32 + (l >> 2);
  const int scol = (l & 3) * 8;
  const bf16* gA = A + (size_t)(m0 + srow) * K + scol;
  const bf16* gB = Bt + (size_t)(n0 + srow) * K + scol;
  bf16* lA = As + w * 1024;
  bf16* lB = Bs + w * 1024;

  const f32x4 zero4 = {0.f, 0.f, 0.f, 0.f};
  f32x4 acc[4][4];
#pragma unroll
  for (int i = 0; i < 4; i++)
#pragma unroll
    for (int j = 0; j < 4; j++) acc[i][j] = zero4;

  for (int k0 = 0; k0 < K; k0 += 64) {
    GL2LDS(gA + k0, lA);
    GL2LDS(gA + (size_t)16 * K + k0, lA + 512);
    GL2LDS(gB + k0, lB);
    GL2LDS(gB + (size_t)16 * K + k0, lB + 512);
    GL2LDS(gA + k0 + 32, lA + 4096);
    GL2LDS(gA + (size_t)16 * K + k0 + 32, lA + 4096 + 512);
    GL2LDS(gB + k0 + 32, lB + 4096);
    GL2LDS(gB + (size_t)16 * K + k0 + 32, lB + 4096 + 512);
    __syncthreads();
#pragma unroll
    for (int hh = 0; hh < 2; hh++) {
      bf16x8 af[4], bfr[4];
#pragma unroll
      for (int i = 0; i < 4; i++)
        af[i] = *(const bf16x8*)(As + hh * 4096 + (wr + i * 16 + c) * 32 + g * 8);
#pragma unroll
      for (int j = 0; j < 4; j++)
        bfr[j] = *(const bf16x8*)(Bs + hh * 4096 + (wc + j * 16 + c) * 32 + g * 8);
#pragma unroll
      for (int i = 0; i < 4; i++)
#pragma unroll
        for (int j = 0; j < 4; j++)
          acc[i][j] = __builtin_amdgcn_mfma_f32_16x16x32_bf16(af[i], bfr[j], acc[i][j], 0, 0, 0);
    }
    __syncthreads();
  }
  float* Cf = (float*)Cv;
  bf16* Cb = (bf16*)Cv;
#pragma unroll
  for (int i = 0; i < 4; i++) {
    const int mb = m0 + wr + i * 16 + g * 4;
#pragma unroll
    for (int j = 0; j < 4; j++) {
      const int n = n0 + wc + j * 16 + c;
      const float bv = BIAS ? bias[n] : 0.f;
#pragma unroll
      for (int r = 0; r < 4; r++) {
        float v = acc[i][j][r] + bv;
        if (ACT == 1) v = gelu_f(v);
        if (ACT == 2) v *= 0.18033688011112042f;  // 0.125*log2(e)
        const size_t idx = (size_t)(mb + r) * N + n;
        if (OUT == 0) {
          float* cp = Cf + idx;
          if (RES) v += *cp;
          *cp = v;
        } else if (OUT == 3) {
          bf16* cp = Cb + idx;
          v += (float)*cp;     // bf16 residual, f32 accumulate
          *cp = (bf16)v;
        } else {
          Cb[idx] = (bf16)v;
        }
      }
    }
  }
}

// ---------------------------------------------------------------------------
// mega_prep: ALL weight transposes (layers + decoder) + var_W + proj casts +
// input casts, one launch. grid (2048, 35).
// z<24: layer*6+mat; z=24 var_W; z=25 proj x4 (dn*log2e prescale);
// z=26/27 enc/dec input casts; z=28..31 caW*; z=32 fw1; z=33 fw2; z=34 head.
// ---------------------------------------------------------------------------
__global__ __launch_bounds__(256) void mega_prep(
    const float* __restrict__ Wq, const float* __restrict__ Wk,
    const float* __restrict__ Wv, const float* __restrict__ Wo,
    const float* __restrict__ w1, const float* __restrict__ w2,
    const float* __restrict__ var_W, const float* __restrict__ proj,
    const float* __restrict__ in_enc, const float* __restrict__ in_dec,
    const float* __restrict__ caWq, const float* __restrict__ caWk,
    const float* __restrict__ caWv, const float* __restrict__ caWo,
    const float* __restrict__ fw1, const float* __restrict__ fw2,
    const float* __restrict__ hW,
    bf16* __restrict__ WL, bf16* __restrict__ WtVar,
    bf16* __restrict__ projB4, bf16* __restrict__ encB,
    bf16* __restrict__ decB, bf16* __restrict__ WD) {
  const int z = blockIdx.y, bid = blockIdx.x, t = threadIdx.x;
  if (z == 26 || z == 27) {
    const float* src = (z == 26) ? in_enc : in_dec;
    bf16* dst = (z == 26) ? encB : decB;
    const int n = (z == 26) ? 16384 * 1280 : 8192 * 1280;
    int i = (bid * 256 + t) * 4;
    const int stride = gridDim.x * 256 * 4;
    for (; i < n; i += stride) {
      float4 v = *(const float4*)(src + i);
      bf16x4 o;
      o[0] = (bf16)v.x; o[1] = (bf16)v.y; o[2] = (bf16)v.z; o[3] = (bf16)v.w;
      *(bf16x4*)(dst + i) = o;
    }
    return;
  }
  if (z == 25) {  // proj cast, dn*log2e prescale (log2-domain FAVOR)
    const int idx = bid * 256 + t;
    if (idx < 4 * cMP * cDH) {
      const int layer = idx / (cMP * cDH), r = idx % (cMP * cDH);
      const int m = r >> 6;
      projB4[idx] = (bf16)(m < cM ? proj[(size_t)layer * cM * cDH + r] * 0.51006972f : 0.f);
    }
    return;
  }
  __shared__ float tile[32][33];
  const float* W;
  bf16* dst;
  int K, N;
  if (z == 24) {
    W = var_W; dst = WtVar; K = 1280; N = 512;
  } else if (z < 24) {
    const int layer = z / 6, mat = z % 6;
    bf16* base = WL + (size_t)layer * 3145728;
    if (mat < 4) {
      W = (mat == 0 ? Wq : mat == 1 ? Wk : mat == 2 ? Wv : Wo) + (size_t)layer * 262144;
      dst = base + mat * 262144; K = 512; N = 512;
    } else if (mat == 4) {
      W = w1 + (size_t)layer * 1048576; dst = base + 1048576; K = 512; N = 2048;
    } else {
      W = w2 + (size_t)layer * 1048576; dst = base + 2097152; K = 2048; N = 512;
    }
  } else {  // z = 28..34: decoder weights
    const int d = z - 28;
    if (d < 4) {
      W = (d == 0 ? caWq : d == 1 ? caWk : d == 2 ? caWv : caWo);
      dst = WD + d * 262144; K = 512; N = 512;
    } else if (d == 4) {
      W = fw1; dst = WD + 1048576; K = 512; N = 2048;
    } else if (d == 5) {
      W = fw2; dst = WD + 2097152; K = 2048; N = 512;
    } else {
      W = hW; dst = WD + 3145728; K = 512; N = 128;
    }
  }
  const int nt = N >> 5;
  if (bid >= nt * (K >> 5)) return;
  const int n0 = (bid % nt) * 32, k0 = (bid / nt) * 32;
  const int tx = t & 31, ty = t >> 5;
#pragma unroll
  for (int i = ty; i < 32; i += 8) tile[i][tx] = W[(size_t)(k0 + i) * N + n0 + tx];
  __syncthreads();
#pragma unroll
  for (int i = ty; i < 32; i += 8)
    dst[(size_t)(n0 + i) * K + k0 + tx] = (bf16)tile[tx][i];
}

// ---------------------------------------------------------------------------
// favor_prep: fused V head-transpose (blocks x<32) + k global max (x>=32).
// kd is computed in log2 domain (projB prescaled); max is monotone-consistent.
// ---------------------------------------------------------------------------
__global__ __launch_bounds__(256) void favor_prep(
    const bf16* __restrict__ QKV, const bf16* __restrict__ projB,
    bf16* __restrict__ Vt, float* __restrict__ bmax) {
  const int z = blockIdx.y, b = z >> 3, h = z & 7;
  const int t = threadIdx.x;
  const int ld = 1536;
  if (blockIdx.x < 32) {
    __shared__ bf16 tile[64][65];
    const bf16* Vh = QKV + 1024;
    const int s0 = blockIdx.x * 64;
#pragma unroll
    for (int r = t >> 3; r < 64; r += 32) {
      bf16x8 v = *(const bf16x8*)(Vh + ((size_t)b * cSE + s0 + r) * ld + h * cDH + (t & 7) * 8);
#pragma unroll
      for (int e = 0; e < 8; e++) tile[(t & 7) * 8 + e][r] = v[e];
    }
    __syncthreads();
    bf16* vz = Vt + (size_t)z * 80 * cSE;
#pragma unroll
    for (int d = t >> 3; d < 64; d += 32) {
      bf16x8 o;
#pragma unroll
      for (int e = 0; e < 8; e++) o[e] = tile[d][(t & 7) * 8 + e];
      *(bf16x8*)(vz + (size_t)d * cSE + s0 + (t & 7) * 8) = o;
    }
    const int rr = t >> 4, seg = (t & 15) * 4;
    bf16x4 ov;
    const float val = (rr == 0) ? 1.f : 0.f;
    ov[0] = (bf16)val; ov[1] = (bf16)val; ov[2] = (bf16)val; ov[3] = (bf16)val;
    *(bf16x4*)(vz + (size_t)(64 + rr) * cSE + s0 + seg) = ov;
    return;
  }
  __shared__ float sm[4];
  const bf16* Kh = QKV + 512;
  const int xb = blockIdx.x - 32;
  const int s0 = xb * 128;
  const int l = t & 63, w = t >> 6, g = l >> 4, c = l & 15;
  const int wr = (w >> 1) * 64, wcol = (w & 1) * 144;
  const f32x4 zero4 = {0.f, 0.f, 0.f, 0.f};
  f32x4 acc[4][9];
#pragma unroll
  for (int i = 0; i < 4; i++)
#pragma unroll
    for (int j = 0; j < 9; j++) acc[i][j] = zero4;
  const size_t abase = ((size_t)b * cSE + s0) * ld + h * cDH;
#pragma unroll
  for (int k0 = 0; k0 < 64; k0 += 32) {
    bf16x8 af[4];
#pragma unroll
    for (int i = 0; i < 4; i++)
      af[i] = *(const bf16x8*)(Kh + abase + (size_t)(wr + i * 16 + c) * ld + k0 + g * 8);
#pragma unroll
    for (int j = 0; j < 9; j++) {
      bf16x8 bfr = *(const bf16x8*)(projB + (wcol + j * 16 + c) * 64 + k0 + g * 8);
#pragma unroll
      for (int i = 0; i < 4; i++)
        acc[i][j] = __builtin_amdgcn_mfma_f32_16x16x32_bf16(af[i], bfr, acc[i][j], 0, 0, 0);
    }
  }
  float m = -3e38f;
#pragma unroll
  for (int i = 0; i < 4; i++)
#pragma unroll
    for (int j = 0; j < 9; j++) {
      const int mc = wcol + j * 16 + c;
      if (mc < cM) {
#pragma unroll
        for (int r = 0; r < 4; r++) m = fmaxf(m, acc[i][j][r]);
      }
    }
  m = wave_max(m);
  if (l == 0) sm[w] = m;
  __syncthreads();
  if (t == 0)
    bmax[z * 16 + xb] = fmaxf(fmaxf(sm[0], sm[1]), fmaxf(sm[2], sm[3]));
}

// ---------------------------------------------------------------------------
// FUSED phi(k) + kv accumulate; log2-domain exp; bf16 partials; K prefetch.
// ---------------------------------------------------------------------------
__global__ __launch_bounds__(256, 1) void favor_kkv(
    const bf16* __restrict__ Kh, int ld, const bf16* __restrict__ projB,
    const bf16* __restrict__ Vt, const float* __restrict__ bmax,
    bf16* __restrict__ part) {
  __shared__ bf16 kp[288 * 72];
  __shared__ float sm[4];
  const int z = blockIdx.y, b = z >> 3, h = z & 7;
  const int chunk = blockIdx.x;
  const int t = threadIdx.x, l = t & 63, w = t >> 6, g = l >> 4, c = l & 15;
  float gm;
  {
    float m = -1e30f;
    for (int i = t; i < 1024; i += 256) m = fmaxf(m, bmax[i]);
    m = wave_max(m);
    if (l == 0) sm[w] = m;
    __syncthreads();
    gm = fmaxf(fmaxf(sm[0], sm[1]), fmaxf(sm[2], sm[3]));
  }
  const int pr = (w >> 1) * 32;
  const int wcol = (w & 1) * 144;
  const int wm = (w & 1) * 144, wd = (w >> 1) * 32;
  const bool dden = (wd == 32);
  const float ratio = 0.061313927f;    // 266^-0.5
  const float DIAG2 = 0.09016844f;     // 0.0625 * log2(e)
  const f32x4 zero4 = {0.f, 0.f, 0.f, 0.f};
  f32x4 kacc[9][2], kaccx[9];
#pragma unroll
  for (int j = 0; j < 9; j++) {
    kacc[j][0] = zero4; kacc[j][1] = zero4; kaccx[j] = zero4;
  }
  const size_t kbase = (size_t)b * cSE * ld + h * cDH;
  const size_t vtz = (size_t)z * 80 * cSE;

  bf16x8 afp[4];  // prefetched K fragments: [k0i*2 + i]
  auto LOADK = [&](int sg) {
#pragma unroll
    for (int k0i = 0; k0i < 2; k0i++)
#pragma unroll
      for (int i = 0; i < 2; i++)
        afp[k0i * 2 + i] = *(const bf16x8*)(Kh + kbase +
            (size_t)(sg + pr + i * 16 + c) * ld + k0i * 32 + g * 8);
  };
  LOADK(chunk * 256);

  for (int st = 0; st < 256; st += 64) {
    const int sg = chunk * 256 + st;
    bf16x8 af[4];
#pragma unroll
    for (int q = 0; q < 4; q++) af[q] = afp[q];
    if (st + 64 < 256) LOADK(sg + 64);  // prefetch next subtile early (T14)
    f32x4 pacc[2][9];
#pragma unroll
    for (int i = 0; i < 2; i++)
#pragma unroll
      for (int j = 0; j < 9; j++) pacc[i][j] = zero4;
    float sq[2] = {0.f, 0.f};
#pragma unroll
    for (int k0i = 0; k0i < 2; k0i++) {
#pragma unroll
      for (int i = 0; i < 2; i++) {
#pragma unroll
        for (int e = 0; e < 8; e++) {
          const float v = (float)af[k0i * 2 + i][e];
          sq[i] += v * v;
        }
      }
#pragma unroll
      for (int j = 0; j < 9; j++) {
        bf16x8 bfr = *(const bf16x8*)(projB + (wcol + j * 16 + c) * 64 + k0i * 32 + g * 8);
        pacc[0][j] = __builtin_amdgcn_mfma_f32_16x16x32_bf16(af[k0i * 2 + 0], bfr, pacc[0][j], 0, 0, 0);
        pacc[1][j] = __builtin_amdgcn_mfma_f32_16x16x32_bf16(af[k0i * 2 + 1], bfr, pacc[1][j], 0, 0, 0);
      }
    }
#pragma unroll
    for (int i = 0; i < 2; i++) {
      sq[i] += __shfl_xor(sq[i], 16);
      sq[i] += __shfl_xor(sq[i], 32);
    }
    float rowsub[2][4];
#pragma unroll
    for (int i = 0; i < 2; i++)
#pragma unroll
      for (int r = 0; r < 4; r++)
        rowsub[i][r] = gm + DIAG2 * __shfl(sq[i], g * 4 + r);
    __syncthreads();  // prev subtile's phase-2 reads of kp done
#pragma unroll
    for (int i = 0; i < 2; i++)
#pragma unroll
      for (int j = 0; j < 9; j++) {
        const int mc = wcol + j * 16 + c;
        bf16x4 o;
#pragma unroll
        for (int r = 0; r < 4; r++) {
          const float v = (mc < cM)
              ? ratio * (exp2f(pacc[i][j][r] - rowsub[i][r]) + 1e-4f) : 0.f;
          o[r] = (bf16)v;
        }
        *(bf16x4*)(kp + (size_t)mc * 72 + pr + i * 16 + g * 4) = o;
      }
    __syncthreads();
#pragma unroll
    for (int k0 = 0; k0 < 64; k0 += 32) {
      bf16x8 bv0 = *(const bf16x8*)(Vt + vtz + (size_t)(wd + c) * cSE + sg + k0 + g * 8);
      bf16x8 bv1 = *(const bf16x8*)(Vt + vtz + (size_t)(wd + 16 + c) * cSE + sg + k0 + g * 8);
      bf16x8 bvx;
      if (dden)
        bvx = *(const bf16x8*)(Vt + vtz + (size_t)(64 + c) * cSE + sg + k0 + g * 8);
#pragma unroll
      for (int j = 0; j < 9; j++) {
        bf16x8 am = *(const bf16x8*)(kp + (size_t)(wm + j * 16 + c) * 72 + k0 + g * 8);
        kacc[j][0] = __builtin_amdgcn_mfma_f32_16x16x32_bf16(am, bv0, kacc[j][0], 0, 0, 0);
        kacc[j][1] = __builtin_amdgcn_mfma_f32_16x16x32_bf16(am, bv1, kacc[j][1], 0, 0, 0);
        if (dden)
          kaccx[j] = __builtin_amdgcn_mfma_f32_16x16x32_bf16(am, bvx, kaccx[j], 0, 0, 0);
      }
    }
  }
  bf16* po = part + ((size_t)z * 8 + chunk) * (cMP * 80);
#pragma unroll
  for (int j = 0; j < 9; j++)
#pragma unroll
    for (int i = 0; i < 2; i++)
#pragma unroll
      for (int r = 0; r < 4; r++)
        po[(size_t)(wm + j * 16 + g * 4 + r) * 80 + wd + i * 16 + c] = (bf16)kacc[j][i][r];
  if (dden) {
#pragma unroll
    for (int j = 0; j < 9; j++)
#pragma unroll
      for (int r = 0; r < 4; r++)
        po[(size_t)(wm + j * 16 + g * 4 + r) * 80 + 64 + c] = (bf16)kaccx[j][r];
  }
}

// reduce 8 bf16 chunks + transpose: kvT[z,d(80),m]; row 64 = ksum. grid (4,64).
__global__ __launch_bounds__(256) void kv_reduce(
    const bf16* __restrict__ part, bf16* __restrict__ kvT) {
  const int z = blockIdx.y, q = blockIdx.x;
  const bf16* p = part + (size_t)z * 8 * (cMP * 80);
  bf16* o = kvT + (size_t)z * 80 * cMP;
  const int lo = q * 5760, hi = lo + 5760;  // cMP*80/4
  for (int idx = lo + threadIdx.x; idx < hi; idx += 256) {
    const int m = idx / 80, d = idx - m * 80;
    float s = 0.f;
#pragma unroll
    for (int cc = 0; cc < 8; cc++) s += (float)p[idx + (size_t)cc * (cMP * 80)];
    o[(size_t)d * cMP + m] = (bf16)s;
  }
}

// ---------------------------------------------------------------------------
// Fused phi(q) + output; log2-domain exp.
// ---------------------------------------------------------------------------
__global__ __launch_bounds__(256, 1) void favor_qout(
    const bf16* __restrict__ Qh, int ld, const bf16* __restrict__ projB,
    const bf16* __restrict__ kvT, bf16* __restrict__ Y) {
  __shared__ bf16 Plds[128 * 296];
  __shared__ float rmaxs[4][64];
  __shared__ float denl[128];
  const int z = blockIdx.y, b = z >> 3, h = z & 7;
  const int s0 = blockIdx.x * 128;
  const int t = threadIdx.x, l = t & 63, w = t >> 6, g = l >> 4, c = l & 15;
  const int wr = (w >> 1) * 64, wcol = (w & 1) * 144;
  const f32x4 zero4 = {0.f, 0.f, 0.f, 0.f};
  f32x4 acc[4][9];
#pragma unroll
  for (int i = 0; i < 4; i++)
#pragma unroll
    for (int j = 0; j < 9; j++) acc[i][j] = zero4;
  float sq[4] = {0.f, 0.f, 0.f, 0.f};
  const size_t abase = ((size_t)b * cSE + s0) * ld + h * cDH;
#pragma unroll
  for (int k0 = 0; k0 < 64; k0 += 32) {
    bf16x8 af[4];
#pragma unroll
    for (int i = 0; i < 4; i++) {
      af[i] = *(const bf16x8*)(Qh + abase + (size_t)(wr + i * 16 + c) * ld + k0 + g * 8);
#pragma unroll
      for (int e = 0; e < 8; e++) {
        const float v = (float)af[i][e];
        sq[i] += v * v;
      }
    }
#pragma unroll
    for (int j = 0; j < 9; j++) {
      bf16x8 bfr = *(const bf16x8*)(projB + (wcol + j * 16 + c) * 64 + k0 + g * 8);
#pragma unroll
      for (int i = 0; i < 4; i++)
        acc[i][j] = __builtin_amdgcn_mfma_f32_16x16x32_bf16(af[i], bfr, acc[i][j], 0, 0, 0);
    }
  }
#pragma unroll
  for (int i = 0; i < 4; i++) {
    sq[i] += __shfl_xor(sq[i], 16);
    sq[i] += __shfl_xor(sq[i], 32);
  }
  const float ratio = 0.061313927f;    // 266^-0.5
  const float DIAG2 = 0.09016844f;     // 0.0625 * log2(e)
  float rowsub[4][4];
#pragma unroll
  for (int i = 0; i < 4; i++)
#pragma unroll
    for (int r = 0; r < 4; r++) {
      float m = -3e38f;
#pragma unroll
      for (int j = 0; j < 9; j++) {
        const int mc = wcol + j * 16 + c;
        m = (mc < cM) ? fmaxf(m, acc[i][j][r]) : m;
      }
      m = fmaxf(m, __shfl_xor(m, 1));
      m = fmaxf(m, __shfl_xor(m, 2));
      m = fmaxf(m, __shfl_xor(m, 4));
      m = fmaxf(m, __shfl_xor(m, 8));
      rowsub[i][r] = m;
    }
  if (c == 0) {
#pragma unroll
    for (int i = 0; i < 4; i++)
#pragma unroll
      for (int r = 0; r < 4; r++) rmaxs[w][i * 16 + g * 4 + r] = rowsub[i][r];
  }
  __syncthreads();
#pragma unroll
  for (int i = 0; i < 4; i++)
#pragma unroll
    for (int r = 0; r < 4; r++) {
      const int row = i * 16 + g * 4 + r;
      rowsub[i][r] = fmaxf(rowsub[i][r], rmaxs[w ^ 1][row]) +
                     DIAG2 * __shfl(sq[i], g * 4 + r);
    }
#pragma unroll
  for (int i = 0; i < 4; i++)
#pragma unroll
    for (int j = 0; j < 9; j++) {
      const int mc = wcol + j * 16 + c;
#pragma unroll
      for (int r = 0; r < 4; r++) {
        const float v = (mc < cM)
            ? ratio * (exp2f(acc[i][j][r] - rowsub[i][r]) + 1e-4f) : 0.f;
        Plds[(wr + i * 16 + g * 4 + r) * 296 + mc] = (bf16)v;
      }
    }
  __syncthreads();

  const int wd = (w & 1) * 32;
  const bool dden = (wd == 32);
  f32x4 acc2[4][2], accx[4];
#pragma unroll
  for (int i = 0; i < 4; i++) {
    acc2[i][0] = zero4; acc2[i][1] = zero4; accx[i] = zero4;
  }
  const size_t kz = (size_t)z * 80 * cMP;
#pragma unroll 3
  for (int k0 = 0; k0 < cMP; k0 += 32) {
    bf16x8 bv[2], bvx;
#pragma unroll
    for (int j = 0; j < 2; j++)
      bv[j] = *(const bf16x8*)(kvT + kz + (size_t)(wd + j * 16 + c) * cMP + k0 + g * 8);
    if (dden)
      bvx = *(const bf16x8*)(kvT + kz + (size_t)(64 + c) * cMP + k0 + g * 8);
#pragma unroll
    for (int i = 0; i < 4; i++) {
      bf16x8 av = *(const bf16x8*)(Plds + (wr + i * 16 + c) * 296 + k0 + g * 8);
      acc2[i][0] = __builtin_amdgcn_mfma_f32_16x16x32_bf16(av, bv[0], acc2[i][0], 0, 0, 0);
      acc2[i][1] = __builtin_amdgcn_mfma_f32_16x16x32_bf16(av, bv[1], acc2[i][1], 0, 0, 0);
      if (dden)
        accx[i] = __builtin_amdgcn_mfma_f32_16x16x32_bf16(av, bvx, accx[i], 0, 0, 0);
    }
  }
  if (dden && c == 0) {
#pragma unroll
    for (int i = 0; i < 4; i++)
#pragma unroll
      for (int r = 0; r < 4; r++)
        denl[wr + i * 16 + g * 4 + r] = accx[i][r];
  }
  __syncthreads();
#pragma unroll
  for (int i = 0; i < 4; i++)
#pragma unroll
    for (int r = 0; r < 4; r++) {
      const int row = wr + i * 16 + g * 4 + r;
      const float inv = 1.0f / denl[row];
#pragma unroll
      for (int j = 0; j < 2; j++)
        Y[((size_t)b * cSE + s0 + row) * cD + h * cDH + wd + j * 16 + c] =
            (bf16)(acc2[i][j][r] * inv);
    }
}

// ---------------------------------------------------------------------------
// LayerNorm rows of 512, bf16 in / bf16 out (f32 stats). ADD: bf16 residual.
// ---------------------------------------------------------------------------
template <bool ADD>
__global__ __launch_bounds__(256) void ln_rows_b(
    const bf16* __restrict__ in, const bf16* __restrict__ add,
    const float* __restrict__ g, const float* __restrict__ be,
    bf16* __restrict__ out) {
  const int wid = blockIdx.x * 4 + (threadIdx.x >> 6);
  const int lane = threadIdx.x & 63;
  bf16x8 iv = *(const bf16x8*)(in + (size_t)wid * cD + lane * 8);
  float x[8];
#pragma unroll
  for (int i = 0; i < 8; i++) x[i] = (float)iv[i];
  if (ADD) {
    bf16x8 av = *(const bf16x8*)(add + (size_t)wid * cD + lane * 8);
#pragma unroll
    for (int i = 0; i < 8; i++) x[i] += (float)av[i];
  }
  float s = 0;
#pragma unroll
  for (int i = 0; i < 8; i++) s += x[i];
  s = wave_sum(s);
  const float mu = s * (1.0f / cD);
  float vs = 0;
#pragma unroll
  for (int i = 0; i < 8; i++) { const float d = x[i] - mu; vs += d * d; }
  vs = wave_sum(vs);
  const float rstd = 1.0f / sqrtf(vs * (1.0f / cD) + 1e-5f);
  bf16x8 ov;
#pragma unroll
  for (int i = 0; i < 8; i++) {
    const int d = lane * 8 + i;
    ov[i] = (bf16)((x[i] - mu) * rstd * g[d] + be[d]);
  }
  *(bf16x8*)(out + (size_t)wid * cD + lane * 8) = ov;
}

// LN of (enc + sinusoidal(expr)), in-place on bf16 X.
__global__ __launch_bounds__(256) void embed_ln_b(
    bf16* __restrict__ X, const int* __restrict__ ids,
    const float* __restrict__ g, const float* __restrict__ be) {
  const int wid = blockIdx.x * 4 + (threadIdx.x >> 6);
  const int lane = threadIdx.x & 63;
  const float idv = (float)ids[wid];
  bf16* xp = X + (size_t)wid * cD + lane * 8;
  bf16x8 iv = *(const bf16x8*)xp;
  float x[8];
#pragma unroll
  for (int i = 0; i < 8; i++) x[i] = (float)iv[i];
  const float kf = -0.03597789207803197f;  // -ln(10000)/256
#pragma unroll
  for (int i = 0; i < 8; i++) {
    const int d = lane * 8 + i;
    float e;
    if (d < 256) e = sinf(idv * expf(kf * (float)d));
    else         e = cosf(idv * expf(kf * (float)(d - 256)));
    x[i] += e;
  }
  float s = 0;
#pragma unroll
  for (int i = 0; i < 8; i++) s += x[i];
  s = wave_sum(s);
  const float mu = s * (1.0f / cD);
  float vs = 0;
#pragma unroll
  for (int i = 0; i < 8; i++) { const float d = x[i] - mu; vs += d * d; }
  vs = wave_sum(vs);
  const float rstd = 1.0f / sqrtf(vs * (1.0f / cD) + 1e-5f);
  bf16x8 ov;
#pragma unroll
  for (int i = 0; i < 8; i++) {
    const int d = lane * 8 + i;
    ov[i] = (bf16)((x[i] - mu) * rstd * g[d] + be[d]);
  }
  *(bf16x8*)xp = ov;
}

// ---------------------------------------------------------------------------
// bf16 MFMA flash cross-attention (unchanged).
// ---------------------------------------------------------------------------
__global__ __launch_bounds__(256) void flash_mfma(
    const bf16* __restrict__ Q, const bf16* __restrict__ Kc,
    const bf16* __restrict__ Vc, bf16* __restrict__ O, int ldkv) {
  __shared__ __align__(16) bf16 KP[4 * 16 * 136];  // K (16KB) ∪ P (17.4KB)
  __shared__ __align__(16) bf16 Vs[80 * 136];      // [d][s] padded; row 64 = ones
  const int id = blockIdx.x;
  const int b = (id & 63) >> 3, h = id & 7, qb = id >> 6;
  const int t = threadIdx.x, l = t & 63, w = t >> 6, g = l >> 4, c = l & 15;
  const int q0 = qb * 64 + w * 16;
  bf16x8 aq[2];
  {
    const bf16* qp = Q + ((size_t)b * cSD + q0 + c) * cD + h * cDH + g * 8;
    aq[0] = *(const bf16x8*)qp;
    aq[1] = *(const bf16x8*)(qp + 32);
  }
  for (int idx = t; idx < 16 * 136; idx += 256) {
    const int rr = idx / 136, cc = idx - rr * 136;
    Vs[(64 + rr) * 136 + cc] = (bf16)(rr == 0 ? 1.f : 0.f);
  }
  const f32x4 zero4 = {0.f, 0.f, 0.f, 0.f};
  f32x4 o5[5];
#pragma unroll
  for (int j = 0; j < 5; j++) o5[j] = zero4;
  float mrow[4];
#pragma unroll
  for (int r = 0; r < 4; r++) mrow[r] = -1e30f;

  const int kr = t >> 1, kof = (t & 1) * 32;
  const int sidx = t & 31, dseg = t >> 5;
  const size_t kvbase = (size_t)b * cSE * ldkv + h * cDH;
  char* KsC = (char*)KP;
  bf16* Pw = KP + w * 16 * 136;
  const float T2 = 11.541560327111708f;   // 8 * log2(e)

  bf16x8 pk[4], pv[4];
  auto LOADR = [&](int kt) {
    const bf16* kp = Kc + kvbase + (size_t)(kt + kr) * ldkv + kof;
#pragma unroll
    for (int i = 0; i < 4; i++) pk[i] = *(const bf16x8*)(kp + i * 8);
    const bf16* vp = Vc + kvbase + (size_t)(kt + 4 * sidx) * ldkv + dseg * 8;
#pragma unroll
    for (int i = 0; i < 4; i++) pv[i] = *(const bf16x8*)(vp + (size_t)i * ldkv);
  };
  auto WRITEL = [&]() {
    const int sw = (kr & 7) << 4;
#pragma unroll
    for (int i = 0; i < 4; i++)
      *(bf16x8*)(KsC + kr * 128 + (((kof + i * 8) * 2) ^ sw)) = pk[i];
#pragma unroll
    for (int e = 0; e < 8; e++) {
      bf16x4 q4;
      q4[0] = pv[0][e]; q4[1] = pv[1][e]; q4[2] = pv[2][e]; q4[3] = pv[3][e];
      *(bf16x4*)(Vs + (dseg * 8 + e) * 136 + 4 * sidx) = q4;
    }
  };
  LOADR(0);
  WRITEL();

  for (int kt = 0; kt < cSE; kt += 128) {
    const bool more = (kt + 128 < cSE);
    if (more) LOADR(kt + 128);
    __syncthreads();              // A: staged tile visible
    f32x4 s4[8];
    __builtin_amdgcn_s_setprio(1);
#pragma unroll
    for (int t2 = 0; t2 < 8; t2++) {
      const int kr2 = t2 * 16 + c;
      const int sw2 = (kr2 & 7) << 4;
      bf16x8 bk0 = *(const bf16x8*)(KsC + kr2 * 128 + ((g * 16) ^ sw2));
      bf16x8 bk1 = *(const bf16x8*)(KsC + kr2 * 128 + ((64 + g * 16) ^ sw2));
      f32x4 z = zero4;
      z = __builtin_amdgcn_mfma_f32_16x16x32_bf16(aq[0], bk0, z, 0, 0, 0);
      z = __builtin_amdgcn_mfma_f32_16x16x32_bf16(aq[1], bk1, z, 0, 0, 0);
      s4[t2] = z;
    }
    __builtin_amdgcn_s_setprio(0);
    __syncthreads();              // B: all K reads done; P may overwrite
#pragma unroll
    for (int r = 0; r < 4; r++) {
      float xv[8];
#pragma unroll
      for (int t2 = 0; t2 < 8; t2++) xv[t2] = s4[t2][r];
      float tm = xv[0];
#pragma unroll
      for (int t2 = 1; t2 < 8; t2++) tm = fmaxf(tm, xv[t2]);
      tm = fmaxf(tm, __shfl_xor(tm, 1));
      tm = fmaxf(tm, __shfl_xor(tm, 2));
      tm = fmaxf(tm, __shfl_xor(tm, 4));
      tm = fmaxf(tm, __shfl_xor(tm, 8));
      if (tm > mrow[r] + T2) {
        const float corr = exp2f(mrow[r] - tm);
        mrow[r] = tm;
#pragma unroll
        for (int j = 0; j < 5; j++) o5[j][r] *= corr;
      }
      const float m = mrow[r];
      const int qr = g * 4 + r;
#pragma unroll
      for (int t2 = 0; t2 < 8; t2++)
        Pw[qr * 136 + t2 * 16 + c] = (bf16)exp2f(xv[t2] - m);
    }
    bf16x8 pa[4];
#pragma unroll
    for (int ks = 0; ks < 4; ks++)
      pa[ks] = *(const bf16x8*)(Pw + c * 136 + ks * 32 + g * 8);
    __builtin_amdgcn_s_setprio(1);
#pragma unroll
    for (int j = 0; j < 5; j++) {
#pragma unroll
      for (int ks = 0; ks < 4; ks++) {
        bf16x8 bv = *(const bf16x8*)(Vs + (j * 16 + c) * 136 + ks * 32 + g * 8);
        o5[j] = __builtin_amdgcn_mfma_f32_16x16x32_bf16(pa[ks], bv, o5[j], 0, 0, 0);
      }
    }
    __builtin_amdgcn_s_setprio(0);
    __syncthreads();              // C: P/Vs reads done; next stage may write
    if (more) WRITEL();
  }
#pragma unroll
  for (int r = 0; r < 4; r++) {
    const float den = __shfl(o5[4][r], l & 48);
    const float inv = 1.0f / den;
    const size_t row = (size_t)b * cSD + q0 + g * 4 + r;
#pragma unroll
    for (int j = 0; j < 4; j++)
      O[row * cD + h * cDH + j * 16 + c] = (bf16)(o5[j][r] * inv);
  }
}

// ---------------------------------------------------------------------------
extern "C" void kernel_launch(void* const* d_in, const int* in_sizes, int n_in,
                              void* d_out, int out_size, void* d_ws, size_t ws_size,
                              hipStream_t stream) {
  const float* in_enc = (const float*)d_in[0];
  const float* in_dec = (const float*)d_in[1];
  const int* expr = (const int*)d_in[2];
  const float* var_W = (const float*)d_in[3];
  const float* var_b = (const float*)d_in[4];
  const float* enc_g = (const float*)d_in[5];
  const float* enc_b = (const float*)d_in[6];
  const float* dec_g = (const float*)d_in[7];
  const float* dec_b = (const float*)d_in[8];
  const float* ln1_g = (const float*)d_in[9];
  const float* ln1_b = (const float*)d_in[10];
  const float* Wq = (const float*)d_in[11];
  const float* Wk = (const float*)d_in[12];
  const float* Wv = (const float*)d_in[13];
  const float* Wo = (const float*)d_in[14];
  const float* bo = (const float*)d_in[15];
  const float* ln2_g = (const float*)d_in[16];
  const float* ln2_b = (const float*)d_in[17];
  const float* w1 = (const float*)d_in[18];
  const float* b1 = (const float*)d_in[19];
  const float* w2 = (const float*)d_in[20];
  const float* b2 = (const float*)d_in[21];
  const float* proj = (const float*)d_in[22];
  const float* caWq = (const float*)d_in[23];
  const float* caWk = (const float*)d_in[24];
  const float* caWv = (const float*)d_in[25];
  const float* caWo = (const float*)d_in[26];
  const float* cabo = (const float*)d_in[27];
  const float* crg = (const float*)d_in[28];
  const float* crb = (const float*)d_in[29];
  const float* fw1 = (const float*)d_in[30];
  const float* fb1 = (const float*)d_in[31];
  const float* fw2 = (const float*)d_in[32];
  const float* fb2 = (const float*)d_in[33];
  const float* og = (const float*)d_in[34];
  const float* ob = (const float*)d_in[35];
  const float* hW = (const float*)d_in[36];
  const float* hb = (const float*)d_in[37];

  // ---- workspace layout (f32 units) --------------------------------------
  float* base  = (float*)d_ws;
  bf16*  Xr    = (bf16*)base;              // [16384,512] bf16 residual stream
  bf16*  Dt1   = Xr + 8388608;             // [8192,512] bf16 (contig after Xr)
  bf16*  Dt2   = Dt1 + 4194304;            // [8192,512] bf16 decoder temp
  bf16*  QKV   = (bf16*)(base + 12582912); // [16384,1536] bf16 fused
  bf16*  Vt    = QKV + 25165824;           // [64,80,2048] bf16
  bf16*  Pb    = Vt + 10485760;            // arena 50331648 bf16
  float* part  = (float*)(Pb + 50331648);  // region (bf16 partials overlay)
  bf16*  kvT   = (bf16*)(part + 11796480); // [64,80,288] bf16
  float* bmax  = (float*)(kvT + 1474560);  // [1024+16]
  bf16*  Yb    = (bf16*)(bmax + 1040);     // [16384,512] bf16
  bf16*  DCb   = Yb + 8388608;             // [8192,512] bf16 (LN'd dec)
  bf16*  Wt    = DCb + 4194304;            // [1048576] bf16 arena (var_W^T)
  bf16*  projB4 = Wt + 1048576;            // [4,288,64] bf16
  const size_t need_bytes = (size_t)75458576 * 4;
  if (ws_size < need_bytes) return;

  // Overlays
  bf16* partB = (bf16*)part;         // [64,8,288,80] bf16 partials
  bf16* encB = Pb;                   // [16384,1280] (phase 0)
  bf16* decB = Pb + 20971520;        // [8192,1280]  (phase 0; contig after encB)
  bf16* Pmid = Pb;                   // [16384,2048] (FF mid, layer loop)
  bf16* WL   = Pb + 33554432;        // [4,3145728] bf16 layer weights
  bf16* WD   = Pb + 46137344;        // [3211264] decoder weights (spare tail)
  bf16* Qc   = Pb + 8388608;         // [8192,512] (decoder)
  bf16* KVc  = Pb + 12582912;        // [16384,1024] (decoder)
  bf16* Fb   = Pb + 29360128;        // [8192,512] (decoder)
  bf16* Pm2  = Pb + 8388608;         // [8192,2048] (decoder FF mid; Qc/KVc dead)

  const dim3 blk(256);

  // ---- phase 0: input casts + ALL weight prep (one launch) ---------------
  mega_prep<<<dim3(2048, 35), blk, 0, stream>>>(
      Wq, Wk, Wv, Wo, w1, w2, var_W, proj, in_enc, in_dec,
      caWq, caWk, caWv, caWo, fw1, fw2, hW,
      WL, Wt, projB4, encB, decB, WD);
  // merged embedding GEMM: M=24576 rows (enc 16384 + dec 8192, contiguous)
  gemm_mfma<1, 0, true, false><<<dim3(4, 192), blk, 0, stream>>>(encB, Wt, Xr, nullptr, var_b, 24576, 512, 1280);
  embed_ln_b<<<4096, blk, 0, stream>>>(Xr, expr, enc_g, enc_b);
  ln_rows_b<false><<<2048, blk, 0, stream>>>(Dt1, nullptr, dec_g, dec_b, DCb);

  // ---- encoder layers ----------------------------------------------------
  for (int i = 0; i < cDEPTH; i++) {
    bf16* Wl = WL + (size_t)i * 3145728;
    bf16* projB = projB4 + (size_t)i * (cMP * cDH);
    ln_rows_b<false><<<4096, blk, 0, stream>>>(Xr, nullptr, ln1_g + i * cD, ln1_b + i * cD, Yb);
    // fused QKV GEMM: N=1536, B = [WqT;WkT;WvT]
    gemm_mfma<1, 0, false, false><<<dim3(12, 128), blk, 0, stream>>>(Yb, Wl, QKV, nullptr, nullptr, 16384, 1536, 512);
    // FAVOR+ (Q at +0, K at +512, V at +1024, stride 1536)
    favor_prep<<<dim3(48, 64), blk, 0, stream>>>(QKV, projB, Vt, bmax);
    favor_kkv<<<dim3(8, 64), blk, 0, stream>>>(QKV + 512, 1536, projB, Vt, bmax, partB);
    kv_reduce<<<dim3(4, 64), blk, 0, stream>>>(partB, kvT);
    favor_qout<<<dim3(16, 64), blk, 0, stream>>>(QKV, 1536, projB, kvT, Yb);
    // Wo + bf16 residual RMW into Xr
    gemm_mfma<3, 0, true, false><<<dim3(4, 128), blk, 0, stream>>>(Yb, Wl + 786432, Xr, nullptr, bo + i * cD, 16384, 512, 512);
    // FF
    ln_rows_b<false><<<4096, blk, 0, stream>>>(Xr, nullptr, ln2_g + i * cD, ln2_b + i * cD, Yb);
    gemm_mfma<1, 1, true, false><<<dim3(16, 128), blk, 0, stream>>>(Yb, Wl + 1048576, Pmid, nullptr, b1 + i * cFF, 16384, 2048, 512);
    gemm_mfma<3, 0, true, false><<<dim3(4, 128), blk, 0, stream>>>(Pmid, Wl + 2097152, Xr, nullptr, b2 + i * cD, 16384, 512, 2048);
  }

  // ---- decoder / cross-attention ----------------------------------------
  // Q projection with flash prescale folded in (ACT=2)
  gemm_mfma<1, 2, false, false><<<dim3(4, 64), blk, 0, stream>>>(DCb, WD, Qc, nullptr, nullptr, 8192, 512, 512);
  // fused K+V GEMM reads Xr directly: N=1024, B = [WkT;WvT]
  gemm_mfma<1, 0, false, false><<<dim3(8, 128), blk, 0, stream>>>(Xr, WD + 262144, KVc, nullptr, nullptr, 16384, 1024, 512);
  flash_mfma<<<dim3(1024), blk, 0, stream>>>(Qc, KVc, KVc + 512, Fb, 1024);
  gemm_mfma<1, 0, true, false><<<dim3(4, 64), blk, 0, stream>>>(Fb, WD + 786432, Dt1, nullptr, cabo, 8192, 512, 512);
  ln_rows_b<true><<<2048, blk, 0, stream>>>(Dt1, DCb, crg, crb, Yb);
  gemm_mfma<1, 1, true, false><<<dim3(16, 64), blk, 0, stream>>>(Yb, WD + 1048576, Pm2, nullptr, fb1, 8192, 2048, 512);
  gemm_mfma<1, 0, true, false><<<dim3(4, 64), blk, 0, stream>>>(Pm2, WD + 2097152, Dt2, nullptr, fb2, 8192, 512, 2048);
  ln_rows_b<false><<<2048, blk, 0, stream>>>(Dt2, nullptr, og, ob, Yb);
  gemm_mfma<0, 0, true, false><<<dim3(1, 64), blk, 0, stream>>>(Yb, WD + 3145728, (float*)d_out, nullptr, hb, 8192, 128, 512);
}

// Round 14
// 1814.680 us; speedup vs baseline: 1.0145x; 1.0145x over previous
//
#include <hip/hip_runtime.h>
#include <hip/hip_bf16.h>
#include <math.h>

// Problem constants
constexpr int cB = 8, cSE = 2048, cSD = 1024, cIN = 1280, cD = 512,
              cDEPTH = 4, cH = 8, cDH = 64, cM = 266, cFF = 2048, cNB = 128;
constexpr int cMP = 288;  // cM padded to multiple of 16 (features pad -> 0)

#define DEV __device__ __forceinline__

typedef __bf16 bf16;
typedef __attribute__((ext_vector_type(8))) __bf16 bf16x8;
typedef __attribute__((ext_vector_type(4))) __bf16 bf16x4;
typedef __attribute__((ext_vector_type(2))) __bf16 bf16x2;
typedef __attribute__((ext_vector_type(4))) float f32x4;

DEV float gelu_f(float x) { return 0.5f * x * (1.0f + erff(x * 0.70710678118654752440f)); }

DEV float wave_sum(float v) {
#pragma unroll
  for (int o = 32; o; o >>= 1) v += __shfl_xor(v, o);
  return v;
}
DEV float wave_max(float v) {
#pragma unroll
  for (int o = 32; o; o >>= 1) v = fmaxf(v, __shfl_xor(v, o));
  return v;
}

#define GL2LDS(gp, lp) __builtin_amdgcn_global_load_lds(                    \
    (const __attribute__((address_space(1))) void*)(gp),                    \
    (__attribute__((address_space(3))) void*)(lp), 16, 0, 0)

// ---------------------------------------------------------------------------
// bf16 MFMA GEMM, BK=64 dual-panel staging, XCD-aware bijective swizzle.
// C[M,N] = epi(A[M,K] @ Bt[N,K]^T). M%128==0, N%128==0, K%64==0.
// OUT: 0=f32 C (+RES f32), 1=bf16 C, 3=bf16 C with bf16 residual RMW.
// ACT: 1 = exact GELU, 2 = scale by 0.125*log2(e) (flash Q prescale).
// ---------------------------------------------------------------------------
template <int OUT, int ACT, bool BIAS, bool RES>
__global__ __launch_bounds__(256) void gemm_mfma(
    const bf16* __restrict__ A, const bf16* __restrict__ Bt,
    void* __restrict__ Cv, bf16* __restrict__ Cv2,
    const float* __restrict__ bias, int M, int N, int K) {
  __shared__ bf16 As[2 * 128 * 32];  // two K-half panels, each [128][32]
  __shared__ bf16 Bs[2 * 128 * 32];
  const int t = threadIdx.x, l = t & 63, w = t >> 6;
  const int g = l >> 4, c = l & 15;
  const int nwg = gridDim.x * gridDim.y;
  int id = blockIdx.y * gridDim.x + blockIdx.x;
  if ((nwg & 7) == 0) id = (id & 7) * (nwg >> 3) + (id >> 3);
  const int m0 = (id / gridDim.x) * 128, n0 = (id % gridDim.x) * 128;
  const int wr = (w >> 1) * 64, wc = (w & 1) * 64;
  const int srow = w * 32 + (l >> 2);
  const int scol = (l & 3) * 8;
  const bf16* gA = A + (size_t)(m0 + srow) * K + scol;
  const bf16* gB = Bt + (size_t)(n0 + srow) * K + scol;
  bf16* lA = As + w * 1024;
  bf16* lB = Bs + w * 1024;

  const f32x4 zero4 = {0.f, 0.f, 0.f, 0.f};
  f32x4 acc[4][4];
#pragma unroll
  for (int i = 0; i < 4; i++)
#pragma unroll
    for (int j = 0; j < 4; j++) acc[i][j] = zero4;

  for (int k0 = 0; k0 < K; k0 += 64) {
    GL2LDS(gA + k0, lA);
    GL2LDS(gA + (size_t)16 * K + k0, lA + 512);
    GL2LDS(gB + k0, lB);
    GL2LDS(gB + (size_t)16 * K + k0, lB + 512);
    GL2LDS(gA + k0 + 32, lA + 4096);
    GL2LDS(gA + (size_t)16 * K + k0 + 32, lA + 4096 + 512);
    GL2LDS(gB + k0 + 32, lB + 4096);
    GL2LDS(gB + (size_t)16 * K + k0 + 32, lB + 4096 + 512);
    __syncthreads();
#pragma unroll
    for (int hh = 0; hh < 2; hh++) {
      bf16x8 af[4], bfr[4];
#pragma unroll
      for (int i = 0; i < 4; i++)
        af[i] = *(const bf16x8*)(As + hh * 4096 + (wr + i * 16 + c) * 32 + g * 8);
#pragma unroll
      for (int j = 0; j < 4; j++)
        bfr[j] = *(const bf16x8*)(Bs + hh * 4096 + (wc + j * 16 + c) * 32 + g * 8);
#pragma unroll
      for (int i = 0; i < 4; i++)
#pragma unroll
        for (int j = 0; j < 4; j++)
          acc[i][j] = __builtin_amdgcn_mfma_f32_16x16x32_bf16(af[i], bfr[j], acc[i][j], 0, 0, 0);
    }
    __syncthreads();
  }
  float* Cf = (float*)Cv;
  bf16* Cb = (bf16*)Cv;
#pragma unroll
  for (int i = 0; i < 4; i++) {
    const int mb = m0 + wr + i * 16 + g * 4;
#pragma unroll
    for (int j = 0; j < 4; j++) {
      const int n = n0 + wc + j * 16 + c;
      const float bv = BIAS ? bias[n] : 0.f;
#pragma unroll
      for (int r = 0; r < 4; r++) {
        float v = acc[i][j][r] + bv;
        if (ACT == 1) v = gelu_f(v);
        if (ACT == 2) v *= 0.18033688011112042f;  // 0.125*log2(e)
        const size_t idx = (size_t)(mb + r) * N + n;
        if (OUT == 0) {
          float* cp = Cf + idx;
          if (RES) v += *cp;
          *cp = v;
        } else if (OUT == 3) {
          bf16* cp = Cb + idx;
          v += (float)*cp;     // bf16 residual, f32 accumulate
          *cp = (bf16)v;
        } else {
          Cb[idx] = (bf16)v;
        }
      }
    }
  }
}

// ---------------------------------------------------------------------------
// mega_prep: ALL per-layer weight transposes + var_W + proj casts + the two
// f32->bf16 input casts, one launch. grid (2048, 28); transpose roles
// self-guard on tile count.
// ---------------------------------------------------------------------------
__global__ __launch_bounds__(256) void mega_prep(
    const float* __restrict__ Wq, const float* __restrict__ Wk,
    const float* __restrict__ Wv, const float* __restrict__ Wo,
    const float* __restrict__ w1, const float* __restrict__ w2,
    const float* __restrict__ var_W, const float* __restrict__ proj,
    const float* __restrict__ in_enc, const float* __restrict__ in_dec,
    bf16* __restrict__ WL, bf16* __restrict__ WtVar,
    bf16* __restrict__ projB4, bf16* __restrict__ encB,
    bf16* __restrict__ decB) {
  const int z = blockIdx.y, bid = blockIdx.x, t = threadIdx.x;
  if (z >= 26) {
    const float* src = (z == 26) ? in_enc : in_dec;
    bf16* dst = (z == 26) ? encB : decB;
    const int n = (z == 26) ? 16384 * 1280 : 8192 * 1280;
    int i = (bid * 256 + t) * 4;
    const int stride = gridDim.x * 256 * 4;
    for (; i < n; i += stride) {
      float4 v = *(const float4*)(src + i);
      bf16x4 o;
      o[0] = (bf16)v.x; o[1] = (bf16)v.y; o[2] = (bf16)v.z; o[3] = (bf16)v.w;
      *(bf16x4*)(dst + i) = o;
    }
    return;
  }
  if (z == 25) {
    const int idx = bid * 256 + t;
    if (idx < 4 * cMP * cDH) {
      const int layer = idx / (cMP * cDH), r = idx % (cMP * cDH);
      const int m = r >> 6;
      projB4[idx] = (bf16)(m < cM ? proj[(size_t)layer * cM * cDH + r] * 0.35355339059327373f : 0.f);
    }
    return;
  }
  __shared__ float tile[32][33];
  const float* W;
  bf16* dst;
  int K, N;
  if (z == 24) {
    W = var_W; dst = WtVar; K = 1280; N = 512;
  } else {
    const int layer = z / 6, mat = z % 6;
    bf16* base = WL + (size_t)layer * 3145728;
    if (mat < 4) {
      W = (mat == 0 ? Wq : mat == 1 ? Wk : mat == 2 ? Wv : Wo) + (size_t)layer * 262144;
      dst = base + mat * 262144; K = 512; N = 512;
    } else if (mat == 4) {
      W = w1 + (size_t)layer * 1048576; dst = base + 1048576; K = 512; N = 2048;
    } else {
      W = w2 + (size_t)layer * 1048576; dst = base + 2097152; K = 2048; N = 512;
    }
  }
  const int nt = N >> 5;
  if (bid >= nt * (K >> 5)) return;
  const int n0 = (bid % nt) * 32, k0 = (bid / nt) * 32;
  const int tx = t & 31, ty = t >> 5;
#pragma unroll
  for (int i = ty; i < 32; i += 8) tile[i][tx] = W[(size_t)(k0 + i) * N + n0 + tx];
  __syncthreads();
#pragma unroll
  for (int i = ty; i < 32; i += 8)
    dst[(size_t)(n0 + i) * K + k0 + tx] = (bf16)tile[tx][i];
}

// Decoder weights.
__global__ __launch_bounds__(256) void mega_prep_dec(
    const float* __restrict__ caWq, const float* __restrict__ caWk,
    const float* __restrict__ caWv, const float* __restrict__ caWo,
    const float* __restrict__ fw1, const float* __restrict__ fw2,
    const float* __restrict__ hW, bf16* __restrict__ WD) {
  const int z = blockIdx.y, bid = blockIdx.x, t = threadIdx.x;
  __shared__ float tile[32][33];
  const float* W;
  bf16* dst;
  int K, N;
  if (z < 4) {
    W = (z == 0 ? caWq : z == 1 ? caWk : z == 2 ? caWv : caWo);
    dst = WD + z * 262144; K = 512; N = 512;
  } else if (z == 4) {
    W = fw1; dst = WD + 1048576; K = 512; N = 2048;
  } else if (z == 5) {
    W = fw2; dst = WD + 2097152; K = 2048; N = 512;
  } else {
    W = hW; dst = WD + 3145728; K = 512; N = 128;
  }
  const int nt = N >> 5;
  if (bid >= nt * (K >> 5)) return;
  const int n0 = (bid % nt) * 32, k0 = (bid / nt) * 32;
  const int tx = t & 31, ty = t >> 5;
#pragma unroll
  for (int i = ty; i < 32; i += 8) tile[i][tx] = W[(size_t)(k0 + i) * N + n0 + tx];
  __syncthreads();
#pragma unroll
  for (int i = ty; i < 32; i += 8)
    dst[(size_t)(n0 + i) * K + k0 + tx] = (bf16)tile[tx][i];
}

// ---------------------------------------------------------------------------
// favor_prep: fused V head-transpose (blocks x<32) + k global max (x>=32).
// ---------------------------------------------------------------------------
__global__ __launch_bounds__(256) void favor_prep(
    const bf16* __restrict__ QKV, const bf16* __restrict__ projB,
    bf16* __restrict__ Vt, float* __restrict__ bmax) {
  const int z = blockIdx.y, b = z >> 3, h = z & 7;
  const int t = threadIdx.x;
  const int ld = 1536;
  if (blockIdx.x < 32) {
    __shared__ bf16 tile[64][65];
    const bf16* Vh = QKV + 1024;
    const int s0 = blockIdx.x * 64;
#pragma unroll
    for (int r = t >> 3; r < 64; r += 32) {
      bf16x8 v = *(const bf16x8*)(Vh + ((size_t)b * cSE + s0 + r) * ld + h * cDH + (t & 7) * 8);
#pragma unroll
      for (int e = 0; e < 8; e++) tile[(t & 7) * 8 + e][r] = v[e];
    }
    __syncthreads();
    bf16* vz = Vt + (size_t)z * 80 * cSE;
#pragma unroll
    for (int d = t >> 3; d < 64; d += 32) {
      bf16x8 o;
#pragma unroll
      for (int e = 0; e < 8; e++) o[e] = tile[d][(t & 7) * 8 + e];
      *(bf16x8*)(vz + (size_t)d * cSE + s0 + (t & 7) * 8) = o;
    }
    const int rr = t >> 4, seg = (t & 15) * 4;
    bf16x4 ov;
    const float val = (rr == 0) ? 1.f : 0.f;
    ov[0] = (bf16)val; ov[1] = (bf16)val; ov[2] = (bf16)val; ov[3] = (bf16)val;
    *(bf16x4*)(vz + (size_t)(64 + rr) * cSE + s0 + seg) = ov;
    return;
  }
  __shared__ float sm[4];
  const bf16* Kh = QKV + 512;
  const int xb = blockIdx.x - 32;
  const int s0 = xb * 128;
  const int l = t & 63, w = t >> 6, g = l >> 4, c = l & 15;
  const int wr = (w >> 1) * 64, wcol = (w & 1) * 144;
  const f32x4 zero4 = {0.f, 0.f, 0.f, 0.f};
  f32x4 acc[4][9];
#pragma unroll
  for (int i = 0; i < 4; i++)
#pragma unroll
    for (int j = 0; j < 9; j++) acc[i][j] = zero4;
  const size_t abase = ((size_t)b * cSE + s0) * ld + h * cDH;
#pragma unroll
  for (int k0 = 0; k0 < 64; k0 += 32) {
    bf16x8 af[4];
#pragma unroll
    for (int i = 0; i < 4; i++)
      af[i] = *(const bf16x8*)(Kh + abase + (size_t)(wr + i * 16 + c) * ld + k0 + g * 8);
#pragma unroll
    for (int j = 0; j < 9; j++) {
      bf16x8 bfr = *(const bf16x8*)(projB + (wcol + j * 16 + c) * 64 + k0 + g * 8);
#pragma unroll
      for (int i = 0; i < 4; i++)
        acc[i][j] = __builtin_amdgcn_mfma_f32_16x16x32_bf16(af[i], bfr, acc[i][j], 0, 0, 0);
    }
  }
  float m = -3e38f;
#pragma unroll
  for (int i = 0; i < 4; i++)
#pragma unroll
    for (int j = 0; j < 9; j++) {
      const int mc = wcol + j * 16 + c;
      if (mc < cM) {
#pragma unroll
        for (int r = 0; r < 4; r++) m = fmaxf(m, acc[i][j][r]);
      }
    }
  m = wave_max(m);
  if (l == 0) sm[w] = m;
  __syncthreads();
  if (t == 0)
    bmax[z * 16 + xb] = fmaxf(fmaxf(sm[0], sm[1]), fmaxf(sm[2], sm[3]));
}

// ---------------------------------------------------------------------------
// FUSED phi(k) + kv accumulate, bf16 partials, next-subtile K prefetch.
// ---------------------------------------------------------------------------
__global__ __launch_bounds__(256, 1) void favor_kkv(
    const bf16* __restrict__ Kh, int ld, const bf16* __restrict__ projB,
    const bf16* __restrict__ Vt, const float* __restrict__ bmax,
    bf16* __restrict__ part) {
  __shared__ bf16 kp[288 * 72];
  __shared__ float sm[4];
  const int z = blockIdx.y, b = z >> 3, h = z & 7;
  const int chunk = blockIdx.x;
  const int t = threadIdx.x, l = t & 63, w = t >> 6, g = l >> 4, c = l & 15;
  float gm;
  {
    float m = -1e30f;
    for (int i = t; i < 1024; i += 256) m = fmaxf(m, bmax[i]);
    m = wave_max(m);
    if (l == 0) sm[w] = m;
    __syncthreads();
    gm = fmaxf(fmaxf(sm[0], sm[1]), fmaxf(sm[2], sm[3]));
  }
  const int pr = (w >> 1) * 32;
  const int wcol = (w & 1) * 144;
  const int wm = (w & 1) * 144, wd = (w >> 1) * 32;
  const bool dden = (wd == 32);
  const float ratio = 0.061313927f;  // 266^-0.5
  const f32x4 zero4 = {0.f, 0.f, 0.f, 0.f};
  f32x4 kacc[9][2], kaccx[9];
#pragma unroll
  for (int j = 0; j < 9; j++) {
    kacc[j][0] = zero4; kacc[j][1] = zero4; kaccx[j] = zero4;
  }
  const size_t kbase = (size_t)b * cSE * ld + h * cDH;
  const size_t vtz = (size_t)z * 80 * cSE;

  bf16x8 afp[4];  // prefetched K fragments: [k0i*2 + i]
  auto LOADK = [&](int sg) {
#pragma unroll
    for (int k0i = 0; k0i < 2; k0i++)
#pragma unroll
      for (int i = 0; i < 2; i++)
        afp[k0i * 2 + i] = *(const bf16x8*)(Kh + kbase +
            (size_t)(sg + pr + i * 16 + c) * ld + k0i * 32 + g * 8);
  };
  LOADK(chunk * 256);

  for (int st = 0; st < 256; st += 64) {
    const int sg = chunk * 256 + st;
    bf16x8 af[4];
#pragma unroll
    for (int q = 0; q < 4; q++) af[q] = afp[q];
    if (st + 64 < 256) LOADK(sg + 64);  // prefetch next subtile early (T14)
    // ---- phase 1: kd tile [64 s x 288 m] in registers ----
    f32x4 pacc[2][9];
#pragma unroll
    for (int i = 0; i < 2; i++)
#pragma unroll
      for (int j = 0; j < 9; j++) pacc[i][j] = zero4;
    float sq[2] = {0.f, 0.f};
#pragma unroll
    for (int k0i = 0; k0i < 2; k0i++) {
#pragma unroll
      for (int i = 0; i < 2; i++) {
#pragma unroll
        for (int e = 0; e < 8; e++) {
          const float v = (float)af[k0i * 2 + i][e];
          sq[i] += v * v;
        }
      }
#pragma unroll
      for (int j = 0; j < 9; j++) {
        bf16x8 bfr = *(const bf16x8*)(projB + (wcol + j * 16 + c) * 64 + k0i * 32 + g * 8);
        pacc[0][j] = __builtin_amdgcn_mfma_f32_16x16x32_bf16(af[k0i * 2 + 0], bfr, pacc[0][j], 0, 0, 0);
        pacc[1][j] = __builtin_amdgcn_mfma_f32_16x16x32_bf16(af[k0i * 2 + 1], bfr, pacc[1][j], 0, 0, 0);
      }
    }
#pragma unroll
    for (int i = 0; i < 2; i++) {
      sq[i] += __shfl_xor(sq[i], 16);
      sq[i] += __shfl_xor(sq[i], 32);
    }
    float rowsub[2][4];
#pragma unroll
    for (int i = 0; i < 2; i++)
#pragma unroll
      for (int r = 0; r < 4; r++)
        rowsub[i][r] = gm + 0.0625f * __shfl(sq[i], g * 4 + r);
    __syncthreads();  // prev subtile's phase-2 reads of kp done
#pragma unroll
    for (int i = 0; i < 2; i++)
#pragma unroll
      for (int j = 0; j < 9; j++) {
        const int mc = wcol + j * 16 + c;
        bf16x4 o;
#pragma unroll
        for (int r = 0; r < 4; r++) {
          const float v = (mc < cM)
              ? ratio * (__expf(pacc[i][j][r] - rowsub[i][r]) + 1e-4f) : 0.f;
          o[r] = (bf16)v;
        }
        *(bf16x4*)(kp + (size_t)mc * 72 + pr + i * 16 + g * 4) = o;
      }
    __syncthreads();
    // ---- phase 2: kv += kp^T @ Vt over this subtile ----
#pragma unroll
    for (int k0 = 0; k0 < 64; k0 += 32) {
      bf16x8 bv0 = *(const bf16x8*)(Vt + vtz + (size_t)(wd + c) * cSE + sg + k0 + g * 8);
      bf16x8 bv1 = *(const bf16x8*)(Vt + vtz + (size_t)(wd + 16 + c) * cSE + sg + k0 + g * 8);
      bf16x8 bvx;
      if (dden)
        bvx = *(const bf16x8*)(Vt + vtz + (size_t)(64 + c) * cSE + sg + k0 + g * 8);
#pragma unroll
      for (int j = 0; j < 9; j++) {
        bf16x8 am = *(const bf16x8*)(kp + (size_t)(wm + j * 16 + c) * 72 + k0 + g * 8);
        kacc[j][0] = __builtin_amdgcn_mfma_f32_16x16x32_bf16(am, bv0, kacc[j][0], 0, 0, 0);
        kacc[j][1] = __builtin_amdgcn_mfma_f32_16x16x32_bf16(am, bv1, kacc[j][1], 0, 0, 0);
        if (dden)
          kaccx[j] = __builtin_amdgcn_mfma_f32_16x16x32_bf16(am, bvx, kaccx[j], 0, 0, 0);
      }
    }
  }
  // store partials (bf16)
  bf16* po = part + ((size_t)z * 8 + chunk) * (cMP * 80);
#pragma unroll
  for (int j = 0; j < 9; j++)
#pragma unroll
    for (int i = 0; i < 2; i++)
#pragma unroll
      for (int r = 0; r < 4; r++)
        po[(size_t)(wm + j * 16 + g * 4 + r) * 80 + wd + i * 16 + c] = (bf16)kacc[j][i][r];
  if (dden) {
#pragma unroll
    for (int j = 0; j < 9; j++)
#pragma unroll
      for (int r = 0; r < 4; r++)
        po[(size_t)(wm + j * 16 + g * 4 + r) * 80 + 64 + c] = (bf16)kaccx[j][r];
  }
}

// reduce 8 bf16 chunks + transpose: kvT[z,d(80),m]; row 64 = ksum. grid (4,64).
__global__ __launch_bounds__(256) void kv_reduce(
    const bf16* __restrict__ part, bf16* __restrict__ kvT) {
  const int z = blockIdx.y, q = blockIdx.x;
  const bf16* p = part + (size_t)z * 8 * (cMP * 80);
  bf16* o = kvT + (size_t)z * 80 * cMP;
  const int lo = q * 5760, hi = lo + 5760;  // cMP*80/4
  for (int idx = lo + threadIdx.x; idx < hi; idx += 256) {
    const int m = idx / 80, d = idx - m * 80;
    float s = 0.f;
#pragma unroll
    for (int cc = 0; cc < 8; cc++) s += (float)p[idx + (size_t)cc * (cMP * 80)];
    o[(size_t)d * cMP + m] = (bf16)s;
  }
}

// ---------------------------------------------------------------------------
// Fused phi(q) + output.
// ---------------------------------------------------------------------------
__global__ __launch_bounds__(256, 1) void favor_qout(
    const bf16* __restrict__ Qh, int ld, const bf16* __restrict__ projB,
    const bf16* __restrict__ kvT, bf16* __restrict__ Y) {
  __shared__ bf16 Plds[128 * 296];
  __shared__ float rmaxs[4][64];
  __shared__ float denl[128];
  const int z = blockIdx.y, b = z >> 3, h = z & 7;
  const int s0 = blockIdx.x * 128;
  const int t = threadIdx.x, l = t & 63, w = t >> 6, g = l >> 4, c = l & 15;
  const int wr = (w >> 1) * 64, wcol = (w & 1) * 144;
  const f32x4 zero4 = {0.f, 0.f, 0.f, 0.f};
  f32x4 acc[4][9];
#pragma unroll
  for (int i = 0; i < 4; i++)
#pragma unroll
    for (int j = 0; j < 9; j++) acc[i][j] = zero4;
  float sq[4] = {0.f, 0.f, 0.f, 0.f};
  const size_t abase = ((size_t)b * cSE + s0) * ld + h * cDH;
#pragma unroll
  for (int k0 = 0; k0 < 64; k0 += 32) {
    bf16x8 af[4];
#pragma unroll
    for (int i = 0; i < 4; i++) {
      af[i] = *(const bf16x8*)(Qh + abase + (size_t)(wr + i * 16 + c) * ld + k0 + g * 8);
#pragma unroll
      for (int e = 0; e < 8; e++) {
        const float v = (float)af[i][e];
        sq[i] += v * v;
      }
    }
#pragma unroll
    for (int j = 0; j < 9; j++) {
      bf16x8 bfr = *(const bf16x8*)(projB + (wcol + j * 16 + c) * 64 + k0 + g * 8);
#pragma unroll
      for (int i = 0; i < 4; i++)
        acc[i][j] = __builtin_amdgcn_mfma_f32_16x16x32_bf16(af[i], bfr, acc[i][j], 0, 0, 0);
    }
  }
#pragma unroll
  for (int i = 0; i < 4; i++) {
    sq[i] += __shfl_xor(sq[i], 16);
    sq[i] += __shfl_xor(sq[i], 32);
  }
  const float ratio = 0.061313927f;  // 266^-0.5
  float rowsub[4][4];
#pragma unroll
  for (int i = 0; i < 4; i++)
#pragma unroll
    for (int r = 0; r < 4; r++) {
      float m = -3e38f;
#pragma unroll
      for (int j = 0; j < 9; j++) {
        const int mc = wcol + j * 16 + c;
        m = (mc < cM) ? fmaxf(m, acc[i][j][r]) : m;
      }
      m = fmaxf(m, __shfl_xor(m, 1));
      m = fmaxf(m, __shfl_xor(m, 2));
      m = fmaxf(m, __shfl_xor(m, 4));
      m = fmaxf(m, __shfl_xor(m, 8));
      rowsub[i][r] = m;
    }
  if (c == 0) {
#pragma unroll
    for (int i = 0; i < 4; i++)
#pragma unroll
      for (int r = 0; r < 4; r++) rmaxs[w][i * 16 + g * 4 + r] = rowsub[i][r];
  }
  __syncthreads();
#pragma unroll
  for (int i = 0; i < 4; i++)
#pragma unroll
    for (int r = 0; r < 4; r++) {
      const int row = i * 16 + g * 4 + r;
      rowsub[i][r] = fmaxf(rowsub[i][r], rmaxs[w ^ 1][row]) +
                     0.0625f * __shfl(sq[i], g * 4 + r);
    }
#pragma unroll
  for (int i = 0; i < 4; i++)
#pragma unroll
    for (int j = 0; j < 9; j++) {
      const int mc = wcol + j * 16 + c;
#pragma unroll
      for (int r = 0; r < 4; r++) {
        const float v = (mc < cM)
            ? ratio * (__expf(acc[i][j][r] - rowsub[i][r]) + 1e-4f) : 0.f;
        Plds[(wr + i * 16 + g * 4 + r) * 296 + mc] = (bf16)v;
      }
    }
  __syncthreads();

  const int wd = (w & 1) * 32;
  const bool dden = (wd == 32);
  f32x4 acc2[4][2], accx[4];
#pragma unroll
  for (int i = 0; i < 4; i++) {
    acc2[i][0] = zero4; acc2[i][1] = zero4; accx[i] = zero4;
  }
  const size_t kz = (size_t)z * 80 * cMP;
#pragma unroll 3
  for (int k0 = 0; k0 < cMP; k0 += 32) {
    bf16x8 bv[2], bvx;
#pragma unroll
    for (int j = 0; j < 2; j++)
      bv[j] = *(const bf16x8*)(kvT + kz + (size_t)(wd + j * 16 + c) * cMP + k0 + g * 8);
    if (dden)
      bvx = *(const bf16x8*)(kvT + kz + (size_t)(64 + c) * cMP + k0 + g * 8);
#pragma unroll
    for (int i = 0; i < 4; i++) {
      bf16x8 av = *(const bf16x8*)(Plds + (wr + i * 16 + c) * 296 + k0 + g * 8);
      acc2[i][0] = __builtin_amdgcn_mfma_f32_16x16x32_bf16(av, bv[0], acc2[i][0], 0, 0, 0);
      acc2[i][1] = __builtin_amdgcn_mfma_f32_16x16x32_bf16(av, bv[1], acc2[i][1], 0, 0, 0);
      if (dden)
        accx[i] = __builtin_amdgcn_mfma_f32_16x16x32_bf16(av, bvx, accx[i], 0, 0, 0);
    }
  }
  if (dden && c == 0) {
#pragma unroll
    for (int i = 0; i < 4; i++)
#pragma unroll
      for (int r = 0; r < 4; r++)
        denl[wr + i * 16 + g * 4 + r] = accx[i][r];
  }
  __syncthreads();
#pragma unroll
  for (int i = 0; i < 4; i++)
#pragma unroll
    for (int r = 0; r < 4; r++) {
      const int row = wr + i * 16 + g * 4 + r;
      const float inv = 1.0f / denl[row];
#pragma unroll
      for (int j = 0; j < 2; j++)
        Y[((size_t)b * cSE + s0 + row) * cD + h * cDH + wd + j * 16 + c] =
            (bf16)(acc2[i][j][r] * inv);
    }
}

// ---------------------------------------------------------------------------
// LayerNorm rows of 512, bf16 in / bf16 out (f32 stats). ADD: bf16 residual.
// ---------------------------------------------------------------------------
template <bool ADD>
__global__ __launch_bounds__(256) void ln_rows_b(
    const bf16* __restrict__ in, const bf16* __restrict__ add,
    const float* __restrict__ g, const float* __restrict__ be,
    bf16* __restrict__ out) {
  const int wid = blockIdx.x * 4 + (threadIdx.x >> 6);
  const int lane = threadIdx.x & 63;
  bf16x8 iv = *(const bf16x8*)(in + (size_t)wid * cD + lane * 8);
  float x[8];
#pragma unroll
  for (int i = 0; i < 8; i++) x[i] = (float)iv[i];
  if (ADD) {
    bf16x8 av = *(const bf16x8*)(add + (size_t)wid * cD + lane * 8);
#pragma unroll
    for (int i = 0; i < 8; i++) x[i] += (float)av[i];
  }
  float s = 0;
#pragma unroll
  for (int i = 0; i < 8; i++) s += x[i];
  s = wave_sum(s);
  const float mu = s * (1.0f / cD);
  float vs = 0;
#pragma unroll
  for (int i = 0; i < 8; i++) { const float d = x[i] - mu; vs += d * d; }
  vs = wave_sum(vs);
  const float rstd = 1.0f / sqrtf(vs * (1.0f / cD) + 1e-5f);
  bf16x8 ov;
#pragma unroll
  for (int i = 0; i < 8; i++) {
    const int d = lane * 8 + i;
    ov[i] = (bf16)((x[i] - mu) * rstd * g[d] + be[d]);
  }
  *(bf16x8*)(out + (size_t)wid * cD + lane * 8) = ov;
}

// LN of (enc + sinusoidal(expr)), in-place on bf16 X.
__global__ __launch_bounds__(256) void embed_ln_b(
    bf16* __restrict__ X, const int* __restrict__ ids,
    const float* __restrict__ g, const float* __restrict__ be) {
  const int wid = blockIdx.x * 4 + (threadIdx.x >> 6);
  const int lane = threadIdx.x & 63;
  const float idv = (float)ids[wid];
  bf16* xp = X + (size_t)wid * cD + lane * 8;
  bf16x8 iv = *(const bf16x8*)xp;
  float x[8];
#pragma unroll
  for (int i = 0; i < 8; i++) x[i] = (float)iv[i];
  const float kf = -0.03597789207803197f;  // -ln(10000)/256
#pragma unroll
  for (int i = 0; i < 8; i++) {
    const int d = lane * 8 + i;
    float e;
    if (d < 256) e = sinf(idv * expf(kf * (float)d));
    else         e = cosf(idv * expf(kf * (float)(d - 256)));
    x[i] += e;
  }
  float s = 0;
#pragma unroll
  for (int i = 0; i < 8; i++) s += x[i];
  s = wave_sum(s);
  const float mu = s * (1.0f / cD);
  float vs = 0;
#pragma unroll
  for (int i = 0; i < 8; i++) { const float d = x[i] - mu; vs += d * d; }
  vs = wave_sum(vs);
  const float rstd = 1.0f / sqrtf(vs * (1.0f / cD) + 1e-5f);
  bf16x8 ov;
#pragma unroll
  for (int i = 0; i < 8; i++) {
    const int d = lane * 8 + i;
    ov[i] = (bf16)((x[i] - mu) * rstd * g[d] + be[d]);
  }
  *(bf16x8*)xp = ov;
}

// ---------------------------------------------------------------------------
// bf16 MFMA flash cross-attention.
// ---------------------------------------------------------------------------
__global__ __launch_bounds__(256) void flash_mfma(
    const bf16* __restrict__ Q, const bf16* __restrict__ Kc,
    const bf16* __restrict__ Vc, bf16* __restrict__ O, int ldkv) {
  __shared__ __align__(16) bf16 KP[4 * 16 * 136];  // K (16KB) ∪ P (17.4KB)
  __shared__ __align__(16) bf16 Vs[80 * 136];      // [d][s] padded; row 64 = ones
  const int id = blockIdx.x;
  const int b = (id & 63) >> 3, h = id & 7, qb = id >> 6;
  const int t = threadIdx.x, l = t & 63, w = t >> 6, g = l >> 4, c = l & 15;
  const int q0 = qb * 64 + w * 16;
  bf16x8 aq[2];
  {
    const bf16* qp = Q + ((size_t)b * cSD + q0 + c) * cD + h * cDH + g * 8;
    aq[0] = *(const bf16x8*)qp;
    aq[1] = *(const bf16x8*)(qp + 32);
  }
  for (int idx = t; idx < 16 * 136; idx += 256) {
    const int rr = idx / 136, cc = idx - rr * 136;
    Vs[(64 + rr) * 136 + cc] = (bf16)(rr == 0 ? 1.f : 0.f);
  }
  const f32x4 zero4 = {0.f, 0.f, 0.f, 0.f};
  f32x4 o5[5];
#pragma unroll
  for (int j = 0; j < 5; j++) o5[j] = zero4;
  float mrow[4];
#pragma unroll
  for (int r = 0; r < 4; r++) mrow[r] = -1e30f;

  const int kr = t >> 1, kof = (t & 1) * 32;
  const int sidx = t & 31, dseg = t >> 5;
  const size_t kvbase = (size_t)b * cSE * ldkv + h * cDH;
  char* KsC = (char*)KP;
  bf16* Pw = KP + w * 16 * 136;
  const float T2 = 11.541560327111708f;   // 8 * log2(e)

  bf16x8 pk[4], pv[4];
  auto LOADR = [&](int kt) {
    const bf16* kp = Kc + kvbase + (size_t)(kt + kr) * ldkv + kof;
#pragma unroll
    for (int i = 0; i < 4; i++) pk[i] = *(const bf16x8*)(kp + i * 8);
    const bf16* vp = Vc + kvbase + (size_t)(kt + 4 * sidx) * ldkv + dseg * 8;
#pragma unroll
    for (int i = 0; i < 4; i++) pv[i] = *(const bf16x8*)(vp + (size_t)i * ldkv);
  };
  auto WRITEL = [&]() {
    const int sw = (kr & 7) << 4;
#pragma unroll
    for (int i = 0; i < 4; i++)
      *(bf16x8*)(KsC + kr * 128 + (((kof + i * 8) * 2) ^ sw)) = pk[i];
#pragma unroll
    for (int e = 0; e < 8; e++) {
      bf16x4 q4;
      q4[0] = pv[0][e]; q4[1] = pv[1][e]; q4[2] = pv[2][e]; q4[3] = pv[3][e];
      *(bf16x4*)(Vs + (dseg * 8 + e) * 136 + 4 * sidx) = q4;
    }
  };
  LOADR(0);
  WRITEL();

  for (int kt = 0; kt < cSE; kt += 128) {
    const bool more = (kt + 128 < cSE);
    if (more) LOADR(kt + 128);
    __syncthreads();              // A: staged tile visible
    f32x4 s4[8];
    __builtin_amdgcn_s_setprio(1);
#pragma unroll
    for (int t2 = 0; t2 < 8; t2++) {
      const int kr2 = t2 * 16 + c;
      const int sw2 = (kr2 & 7) << 4;
      bf16x8 bk0 = *(const bf16x8*)(KsC + kr2 * 128 + ((g * 16) ^ sw2));
      bf16x8 bk1 = *(const bf16x8*)(KsC + kr2 * 128 + ((64 + g * 16) ^ sw2));
      f32x4 z = zero4;
      z = __builtin_amdgcn_mfma_f32_16x16x32_bf16(aq[0], bk0, z, 0, 0, 0);
      z = __builtin_amdgcn_mfma_f32_16x16x32_bf16(aq[1], bk1, z, 0, 0, 0);
      s4[t2] = z;
    }
    __builtin_amdgcn_s_setprio(0);
    __syncthreads();              // B: all K reads done; P may overwrite
#pragma unroll
    for (int r = 0; r < 4; r++) {
      float xv[8];
#pragma unroll
      for (int t2 = 0; t2 < 8; t2++) xv[t2] = s4[t2][r];
      float tm = xv[0];
#pragma unroll
      for (int t2 = 1; t2 < 8; t2++) tm = fmaxf(tm, xv[t2]);
      tm = fmaxf(tm, __shfl_xor(tm, 1));
      tm = fmaxf(tm, __shfl_xor(tm, 2));
      tm = fmaxf(tm, __shfl_xor(tm, 4));
      tm = fmaxf(tm, __shfl_xor(tm, 8));
      if (tm > mrow[r] + T2) {
        const float corr = exp2f(mrow[r] - tm);
        mrow[r] = tm;
#pragma unroll
        for (int j = 0; j < 5; j++) o5[j][r] *= corr;
      }
      const float m = mrow[r];
      const int qr = g * 4 + r;
#pragma unroll
      for (int t2 = 0; t2 < 8; t2++)
        Pw[qr * 136 + t2 * 16 + c] = (bf16)exp2f(xv[t2] - m);
    }
    bf16x8 pa[4];
#pragma unroll
    for (int ks = 0; ks < 4; ks++)
      pa[ks] = *(const bf16x8*)(Pw + c * 136 + ks * 32 + g * 8);
    __builtin_amdgcn_s_setprio(1);
#pragma unroll
    for (int j = 0; j < 5; j++) {
#pragma unroll
      for (int ks = 0; ks < 4; ks++) {
        bf16x8 bv = *(const bf16x8*)(Vs + (j * 16 + c) * 136 + ks * 32 + g * 8);
        o5[j] = __builtin_amdgcn_mfma_f32_16x16x32_bf16(pa[ks], bv, o5[j], 0, 0, 0);
      }
    }
    __builtin_amdgcn_s_setprio(0);
    __syncthreads();              // C: P/Vs reads done; next stage may write
    if (more) WRITEL();
  }
#pragma unroll
  for (int r = 0; r < 4; r++) {
    const float den = __shfl(o5[4][r], l & 48);
    const float inv = 1.0f / den;
    const size_t row = (size_t)b * cSD + q0 + g * 4 + r;
#pragma unroll
    for (int j = 0; j < 4; j++)
      O[row * cD + h * cDH + j * 16 + c] = (bf16)(o5[j][r] * inv);
  }
}

// ---------------------------------------------------------------------------
extern "C" void kernel_launch(void* const* d_in, const int* in_sizes, int n_in,
                              void* d_out, int out_size, void* d_ws, size_t ws_size,
                              hipStream_t stream) {
  const float* in_enc = (const float*)d_in[0];
  const float* in_dec = (const float*)d_in[1];
  const int* expr = (const int*)d_in[2];
  const float* var_W = (const float*)d_in[3];
  const float* var_b = (const float*)d_in[4];
  const float* enc_g = (const float*)d_in[5];
  const float* enc_b = (const float*)d_in[6];
  const float* dec_g = (const float*)d_in[7];
  const float* dec_b = (const float*)d_in[8];
  const float* ln1_g = (const float*)d_in[9];
  const float* ln1_b = (const float*)d_in[10];
  const float* Wq = (const float*)d_in[11];
  const float* Wk = (const float*)d_in[12];
  const float* Wv = (const float*)d_in[13];
  const float* Wo = (const float*)d_in[14];
  const float* bo = (const float*)d_in[15];
  const float* ln2_g = (const float*)d_in[16];
  const float* ln2_b = (const float*)d_in[17];
  const float* w1 = (const float*)d_in[18];
  const float* b1 = (const float*)d_in[19];
  const float* w2 = (const float*)d_in[20];
  const float* b2 = (const float*)d_in[21];
  const float* proj = (const float*)d_in[22];
  const float* caWq = (const float*)d_in[23];
  const float* caWk = (const float*)d_in[24];
  const float* caWv = (const float*)d_in[25];
  const float* caWo = (const float*)d_in[26];
  const float* cabo = (const float*)d_in[27];
  const float* crg = (const float*)d_in[28];
  const float* crb = (const float*)d_in[29];
  const float* fw1 = (const float*)d_in[30];
  const float* fb1 = (const float*)d_in[31];
  const float* fw2 = (const float*)d_in[32];
  const float* fb2 = (const float*)d_in[33];
  const float* og = (const float*)d_in[34];
  const float* ob = (const float*)d_in[35];
  const float* hW = (const float*)d_in[36];
  const float* hb = (const float*)d_in[37];

  // ---- workspace layout (f32 units) --------------------------------------
  float* base  = (float*)d_ws;
  bf16*  Xr    = (bf16*)base;              // [16384,512] bf16 residual stream
  bf16*  Dt1   = Xr + 8388608;             // [8192,512] bf16 decoder temp
  bf16*  Dt2   = Dt1 + 4194304;            // [8192,512] bf16 decoder temp
  bf16*  QKV   = (bf16*)(base + 12582912); // [16384,1536] bf16 fused
  bf16*  Vt    = QKV + 25165824;           // [64,80,2048] bf16
  bf16*  Pb    = Vt + 10485760;            // arena 50331648 bf16
  float* part  = (float*)(Pb + 50331648);  // region (bf16 partials overlay)
  bf16*  kvT   = (bf16*)(part + 11796480); // [64,80,288] bf16
  float* bmax  = (float*)(kvT + 1474560);  // [1024+16]
  bf16*  Yb    = (bf16*)(bmax + 1040);     // [16384,512] bf16
  bf16*  DCb   = Yb + 8388608;             // [8192,512] bf16 (LN'd dec)
  bf16*  Wt    = DCb + 4194304;            // [1048576] bf16 arena (var_W^T)
  bf16*  projB4 = Wt + 1048576;            // [4,288,64] bf16
  const size_t need_bytes = (size_t)75458576 * 4;
  if (ws_size < need_bytes) return;

  // Overlays
  bf16* partB = (bf16*)part;         // [64,8,288,80] bf16 partials
  bf16* encB = Pb;                   // [16384,1280] (phase 0)
  bf16* decB = (bf16*)part;          // [8192,1280]  (phase 0)
  bf16* Pmid = Pb;                   // [16384,2048] (FF mid, layer loop)
  bf16* WL   = Pb + 33554432;        // [4,3145728] bf16 layer weights
  bf16* Qc   = Pb + 8388608;         // [8192,512]
  bf16* KVc  = Pb + 12582912;        // [16384,1024]
  bf16* Fb   = Pb + 29360128;        // [8192,512]
  bf16* Pm2  = Pb + 33554432;        // [8192,2048] (decoder FF mid; WL dead)
  bf16* WD   = (bf16*)part;          // decoder weights arena (part dead)

  const dim3 blk(256);

  // ---- phase 0: input casts + ALL layer weight prep (one launch) ---------
  mega_prep<<<dim3(2048, 28), blk, 0, stream>>>(Wq, Wk, Wv, Wo, w1, w2, var_W, proj,
                                                in_enc, in_dec, WL, Wt, projB4,
                                                encB, decB);
  gemm_mfma<1, 0, true, false><<<dim3(4, 128), blk, 0, stream>>>(encB, Wt, Xr, nullptr, var_b, 16384, 512, 1280);
  gemm_mfma<1, 0, true, false><<<dim3(4, 64), blk, 0, stream>>>(decB, Wt, Dt1, nullptr, var_b, 8192, 512, 1280);
  embed_ln_b<<<4096, blk, 0, stream>>>(Xr, expr, enc_g, enc_b);
  ln_rows_b<false><<<2048, blk, 0, stream>>>(Dt1, nullptr, dec_g, dec_b, DCb);

  // ---- encoder layers ----------------------------------------------------
  for (int i = 0; i < cDEPTH; i++) {
    bf16* Wl = WL + (size_t)i * 3145728;
    bf16* projB = projB4 + (size_t)i * (cMP * cDH);
    ln_rows_b<false><<<4096, blk, 0, stream>>>(Xr, nullptr, ln1_g + i * cD, ln1_b + i * cD, Yb);
    // fused QKV GEMM: N=1536, B = [WqT;WkT;WvT]
    gemm_mfma<1, 0, false, false><<<dim3(12, 128), blk, 0, stream>>>(Yb, Wl, QKV, nullptr, nullptr, 16384, 1536, 512);
    // FAVOR+ (Q at +0, K at +512, V at +1024, stride 1536)
    favor_prep<<<dim3(48, 64), blk, 0, stream>>>(QKV, projB, Vt, bmax);
    favor_kkv<<<dim3(8, 64), blk, 0, stream>>>(QKV + 512, 1536, projB, Vt, bmax, partB);
    kv_reduce<<<dim3(4, 64), blk, 0, stream>>>(partB, kvT);
    favor_qout<<<dim3(16, 64), blk, 0, stream>>>(QKV, 1536, projB, kvT, Yb);
    // Wo + bf16 residual RMW into Xr
    gemm_mfma<3, 0, true, false><<<dim3(4, 128), blk, 0, stream>>>(Yb, Wl + 786432, Xr, nullptr, bo + i * cD, 16384, 512, 512);
    // FF
    ln_rows_b<false><<<4096, blk, 0, stream>>>(Xr, nullptr, ln2_g + i * cD, ln2_b + i * cD, Yb);
    gemm_mfma<1, 1, true, false><<<dim3(16, 128), blk, 0, stream>>>(Yb, Wl + 1048576, Pmid, nullptr, b1 + i * cFF, 16384, 2048, 512);
    gemm_mfma<3, 0, true, false><<<dim3(4, 128), blk, 0, stream>>>(Pmid, Wl + 2097152, Xr, nullptr, b2 + i * cD, 16384, 512, 2048);
  }

  // ---- decoder / cross-attention ----------------------------------------
  mega_prep_dec<<<dim3(1024, 7), blk, 0, stream>>>(caWq, caWk, caWv, caWo, fw1, fw2, hW, WD);
  // Q projection with flash prescale folded in (ACT=2)
  gemm_mfma<1, 2, false, false><<<dim3(4, 64), blk, 0, stream>>>(DCb, WD, Qc, nullptr, nullptr, 8192, 512, 512);
  // fused K+V GEMM reads Xr directly: N=1024, B = [WkT;WvT]
  gemm_mfma<1, 0, false, false><<<dim3(8, 128), blk, 0, stream>>>(Xr, WD + 262144, KVc, nullptr, nullptr, 16384, 1024, 512);
  flash_mfma<<<dim3(1024), blk, 0, stream>>>(Qc, KVc, KVc + 512, Fb, 1024);
  gemm_mfma<1, 0, true, false><<<dim3(4, 64), blk, 0, stream>>>(Fb, WD + 786432, Dt1, nullptr, cabo, 8192, 512, 512);
  ln_rows_b<true><<<2048, blk, 0, stream>>>(Dt1, DCb, crg, crb, Yb);
  gemm_mfma<1, 1, true, false><<<dim3(16, 64), blk, 0, stream>>>(Yb, WD + 1048576, Pm2, nullptr, fb1, 8192, 2048, 512);
  gemm_mfma<1, 0, true, false><<<dim3(4, 64), blk, 0, stream>>>(Pm2, WD + 2097152, Dt2, nullptr, fb2, 8192, 512, 2048);
  ln_rows_b<false><<<2048, blk, 0, stream>>>(Dt2, nullptr, og, ob, Yb);
  gemm_mfma<0, 0, true, false><<<dim3(1, 64), blk, 0, stream>>>(Yb, WD + 3145728, (float*)d_out, nullptr, hb, 8192, 128, 512);
}